// Round 7
// baseline (239.024 us; speedup 1.0000x reference)
//
#include <hip/hip_runtime.h>

// FWHT over last dim (4096) of [8192, 4096] fp32, normalized by 1/64.
// Round-5 pure-stream shuffle kernel + ONE change: NON-TEMPORAL stores.
// (Round-6 respin: __builtin_nontemporal_store requires a NATIVE vector
//  type, not HIP's float4 class -> use ext_vector_type(4).)
//
// Theory: output writes (128 MiB/iter) allocate into the 256 MiB L3 and
// evict half the 128 MiB input every iteration (FETCH_SIZE = exactly half
// the input, across all 5 prior kernels). Read+write streams thrash the
// L3-allocate path -> structure-independent ~2.4 TB/s cap. `nt` stores
// stream the output to HBM without L3 allocation; input stays L3-resident.
//
// Layout: load instr i gives lane l the float4 at row offset i*256 + 4l,
// i.e. element e = i*256 + 4l + j -> e[1:0]=j (in-reg), e[7:2]=lane,
// e[11:8]=i (across regs). Stages strictly LSB->MSB (same summation tree as
// the reference recursion -> bit-exact):
//   e-bit 0,1   : in-register pairs (r, r^1), (r, r^2)
//   e-bit 2..7  : cross-lane, __shfl_xor masks 1,2,4,8,16,32;
//                 butterfly = fmaf(sgn, own, partner): lo lane own+p = a+b,
//                 hi lane p-own = a-b (fma with +/-1.0 is exact, == a+b/a-b)
//   e-bit 8..11 : in-register pairs (r, r^4), (r, r^8), (r, r^16), (r, r^32)

#define N        4096
#define THREADS  256    // 4 independent waves per block (no barriers)

typedef float nt4 __attribute__((ext_vector_type(4)));   // native vec for nt store

__global__ __launch_bounds__(THREADS)
void FWHT_83476984365427_kernel(const float* __restrict__ x,
                                float* __restrict__ out,
                                int nrows) {
    const int wid = blockIdx.x * (THREADS / 64) + (threadIdx.x >> 6);
    if (wid >= nrows) return;
    const int l = threadIdx.x & 63;

    const float* __restrict__ xr  = x   + (size_t)wid * N;
    float* __restrict__       otr = out + (size_t)wid * N;

    float v[64];

    // ---- Load: 16 x dwordx4, instr i = 1 KB wave-contiguous. Regular
    // (L3-allocating) loads: input is re-read every iteration, keep it cached.
#pragma unroll
    for (int i = 0; i < 16; i++) {
        float4 f = *(const float4*)(xr + i * 256 + l * 4);
        v[4 * i + 0] = f.x;
        v[4 * i + 1] = f.y;
        v[4 * i + 2] = f.z;
        v[4 * i + 3] = f.w;
    }

    // ---- Element bits 0..1: in-register (within each float4).
#pragma unroll
    for (int s = 1; s < 4; s <<= 1) {
#pragma unroll
        for (int k = 0; k < 64; k++) {
            if ((k & s) == 0) {
                float a = v[k];
                float b = v[k + s];
                v[k]     = a + b;
                v[k + s] = a - b;
            }
        }
    }

    // ---- Element bits 2..7: cross-lane butterflies, masks 1..32 (LSB->MSB).
#pragma unroll
    for (int m = 1; m < 64; m <<= 1) {
        const float sgn = (l & m) ? -1.0f : 1.0f;
#pragma unroll
        for (int r = 0; r < 64; r++) {
            float p = __shfl_xor(v[r], m, 64);
            v[r] = fmaf(sgn, v[r], p);   // lo: own+p = a+b ; hi: p-own = a-b
        }
    }

    // ---- Element bits 8..11: in-register (across the 16 float4 chunks).
#pragma unroll
    for (int s = 4; s < 64; s <<= 1) {
#pragma unroll
        for (int k = 0; k < 64; k++) {
            if ((k & s) == 0) {
                float a = v[k];
                float b = v[k + s];
                v[k]     = a + b;
                v[k + s] = a - b;
            }
        }
    }

    // ---- Scale (exact 2^-6) and store NON-TEMPORALLY: 16 x dwordx4 `nt`,
    // 1 KB wave-contiguous per instr (16 full 64B lines -> no partial-line
    // write-combining needed), streamed to HBM without L3 allocation.
    const float scale = 1.0f / 64.0f;
#pragma unroll
    for (int i = 0; i < 16; i++) {
        nt4 f;
        f.x = v[4 * i + 0] * scale;
        f.y = v[4 * i + 1] * scale;
        f.z = v[4 * i + 2] * scale;
        f.w = v[4 * i + 3] * scale;
        __builtin_nontemporal_store(f, (nt4*)(otr + i * 256 + l * 4));
    }
}

extern "C" void kernel_launch(void* const* d_in, const int* in_sizes, int n_in,
                              void* d_out, int out_size, void* d_ws, size_t ws_size,
                              hipStream_t stream) {
    (void)n_in; (void)d_ws; (void)ws_size; (void)out_size;
    const float* x = (const float*)d_in[0];
    float* out = (float*)d_out;
    const int nrows = in_sizes[0] / N;
    const int wpb = THREADS / 64;
    dim3 grid((nrows + wpb - 1) / wpb);
    dim3 block(THREADS);
    FWHT_83476984365427_kernel<<<grid, block, 0, stream>>>(x, out, nrows);
}